// Round 1
// baseline (397.825 us; speedup 1.0000x reference)
//
#include <hip/hip_runtime.h>

#define KE 14.399645351950548f

__global__ __launch_bounds__(256) void mlmm_elec_kernel(
    const float* __restrict__ dist,      // [E]
    const float* __restrict__ vec,       // [E,3]
    const float* __restrict__ q_ml,      // [N_ML]
    const float* __restrict__ q_mm,      // [N_MM]
    const float* __restrict__ mu,        // [N_ML,3]
    const float* __restrict__ quad,      // [N_ML,3,3]
    const int*   __restrict__ idx_u,     // [E]
    const int*   __restrict__ idx_v,     // [E]
    float* __restrict__ out,             // [E]
    int n4)                              // E/4
{
    int t = blockIdx.x * blockDim.x + threadIdx.x;
    if (t >= n4) return;

    // ---- coalesced 16B streaming loads: 4 edges per thread ----
    const float4 r4 = reinterpret_cast<const float4*>(dist)[t];
    const int4   u4 = reinterpret_cast<const int4*>(idx_u)[t];
    const int4   w4 = reinterpret_cast<const int4*>(idx_v)[t];
    // vectors for 4 edges = 12 consecutive floats = 3 float4s
    const float4 va = reinterpret_cast<const float4*>(vec)[3 * t + 0];
    const float4 vb = reinterpret_cast<const float4*>(vec)[3 * t + 1];
    const float4 vc = reinterpret_cast<const float4*>(vec)[3 * t + 2];

    const float rr[4] = {r4.x, r4.y, r4.z, r4.w};
    const float vx[4] = {va.x, va.w, vb.z, vc.y};
    const float vy[4] = {va.y, vb.x, vb.w, vc.z};
    const float vz[4] = {va.z, vb.y, vc.x, vc.w};
    const int   uu[4] = {u4.x, u4.y, u4.z, u4.w};
    const int   ww[4] = {w4.x, w4.y, w4.z, w4.w};

    float res[4];
#pragma unroll
    for (int k = 0; k < 4; ++k) {
        const float r   = rr[k];
        const float r2  = r * r;
        const float B0  = 1.0f / r;
        const float B1  = B0 / r2;
        const float B2  = 3.0f * B1 / r2;

        const int u = uu[k];
        const float qu = q_ml[u];
        const float qv = q_mm[ww[k]];

        // charge-charge
        float e = B0 * qu * qv;

        // dipole
        const float x = vx[k], y = vy[k], z = vz[k];
        const float* m = mu + 3 * u;
        const float g1 = m[0] * x + m[1] * y + m[2] * z;
        e += B1 * g1 * qv;

        // quadrupole: sum_ij Q_ij * (v_i v_j - diag_mean * delta_ij)
        const float* Q = quad + 9 * u;
        const float diag_mean = (x * x + y * y + z * z) * (1.0f / 3.0f);
        const float g2 =
            Q[0] * (x * x - diag_mean) +
            Q[4] * (y * y - diag_mean) +
            Q[8] * (z * z - diag_mean) +
            (Q[1] + Q[3]) * (x * y) +
            (Q[2] + Q[6]) * (x * z) +
            (Q[5] + Q[7]) * (y * z);
        e -= B2 * g2 * qv;

        res[k] = KE * e;
    }

    reinterpret_cast<float4*>(out)[t] =
        make_float4(res[0], res[1], res[2], res[3]);
}

extern "C" void kernel_launch(void* const* d_in, const int* in_sizes, int n_in,
                              void* d_out, int out_size, void* d_ws, size_t ws_size,
                              hipStream_t stream) {
    const float* dist  = (const float*)d_in[0];
    const float* vec   = (const float*)d_in[1];
    const float* q_ml  = (const float*)d_in[2];
    const float* q_mm  = (const float*)d_in[3];
    const float* mu    = (const float*)d_in[4];
    const float* quad  = (const float*)d_in[5];
    const int*   idx_u = (const int*)d_in[6];
    const int*   idx_v = (const int*)d_in[7];
    float* out = (float*)d_out;

    const int E  = in_sizes[0];
    const int n4 = E / 4;           // E = 2^24, divisible by 4
    const int block = 256;
    const int grid  = (n4 + block - 1) / block;

    mlmm_elec_kernel<<<grid, block, 0, stream>>>(
        dist, vec, q_ml, q_mm, mu, quad, idx_u, idx_v, out, n4);
}

// Round 2
// 245.516 us; speedup vs baseline: 1.6204x; 1.6204x over previous
//
#include <hip/hip_runtime.h>

#define KE 14.399645351950548f

// ---------------------------------------------------------------------------
// Pack kernel: per ML atom, gather q, mu, and the 6 independent quadrupole
// combos (with the traceless correction baked in) into one 64B cache line.
//   p[0..3]  = q, mux, muy, muz
//   p[4..7]  = Qxx - tr/3, Qyy - tr/3, Qzz - tr/3, Qxy+Qyx
//   p[8..11] = Qxz+Qzx, Qyz+Qzy, 0, 0
// ---------------------------------------------------------------------------
__global__ __launch_bounds__(256) void pack_ml_kernel(
    const float* __restrict__ q_ml,
    const float* __restrict__ mu,
    const float* __restrict__ quad,
    float* __restrict__ packed,     // [n_ml * 16] floats, 64B rows
    int n_ml)
{
    int i = blockIdx.x * blockDim.x + threadIdx.x;
    if (i >= n_ml) return;
    const float* Q = quad + 9 * i;
    const float tr3 = (Q[0] + Q[4] + Q[8]) * (1.0f / 3.0f);
    float4* p = reinterpret_cast<float4*>(packed + 16 * i);
    p[0] = make_float4(q_ml[i], mu[3 * i + 0], mu[3 * i + 1], mu[3 * i + 2]);
    p[1] = make_float4(Q[0] - tr3, Q[4] - tr3, Q[8] - tr3, Q[1] + Q[3]);
    p[2] = make_float4(Q[2] + Q[6], Q[5] + Q[7], 0.0f, 0.0f);
}

// ---------------------------------------------------------------------------
// Main kernel: 4 edges/thread, all streaming loads 16B, one 64B line per
// ML-atom gather (3 float4s from the packed table), one line for q_mm.
// ---------------------------------------------------------------------------
__global__ __launch_bounds__(256) void mlmm_elec_packed_kernel(
    const float* __restrict__ dist,      // [E]
    const float* __restrict__ vec,       // [E,3]
    const float* __restrict__ packed,    // [N_ML*16] packed ML table
    const float* __restrict__ q_mm,      // [N_MM]
    const int*   __restrict__ idx_u,     // [E]
    const int*   __restrict__ idx_v,     // [E]
    float* __restrict__ out,             // [E]
    int n4)
{
    int t = blockIdx.x * blockDim.x + threadIdx.x;
    if (t >= n4) return;

    const float4 r4 = reinterpret_cast<const float4*>(dist)[t];
    const int4   u4 = reinterpret_cast<const int4*>(idx_u)[t];
    const int4   w4 = reinterpret_cast<const int4*>(idx_v)[t];
    const float4 va = reinterpret_cast<const float4*>(vec)[3 * t + 0];
    const float4 vb = reinterpret_cast<const float4*>(vec)[3 * t + 1];
    const float4 vc = reinterpret_cast<const float4*>(vec)[3 * t + 2];

    const float rr[4] = {r4.x, r4.y, r4.z, r4.w};
    const float vx[4] = {va.x, va.w, vb.z, vc.y};
    const float vy[4] = {va.y, vb.x, vb.w, vc.z};
    const float vz[4] = {va.z, vb.y, vc.x, vc.w};
    const int   uu[4] = {u4.x, u4.y, u4.z, u4.w};
    const int   ww[4] = {w4.x, w4.y, w4.z, w4.w};

    float res[4];
#pragma unroll
    for (int k = 0; k < 4; ++k) {
        const float r  = rr[k];
        const float r2 = r * r;
        const float B0 = 1.0f / r;
        const float B1 = B0 / r2;
        const float B2 = 3.0f * B1 / r2;

        const float4* p = reinterpret_cast<const float4*>(packed + 16 * uu[k]);
        const float4 p0 = p[0];   // q, mux, muy, muz
        const float4 p1 = p[1];   // Q'xx, Q'yy, Q'zz, Qxy2
        const float4 p2 = p[2];   // Qxz2, Qyz2, -, -
        const float qv = q_mm[ww[k]];

        const float x = vx[k], y = vy[k], z = vz[k];
        const float g1 = p0.y * x + p0.z * y + p0.w * z;
        const float g2 = p1.x * (x * x) + p1.y * (y * y) + p1.z * (z * z)
                       + p1.w * (x * y) + p2.x * (x * z) + p2.y * (y * z);

        res[k] = KE * qv * (B0 * p0.x + B1 * g1 - B2 * g2);
    }

    reinterpret_cast<float4*>(out)[t] =
        make_float4(res[0], res[1], res[2], res[3]);
}

// ---------------------------------------------------------------------------
// Fallback (unpacked) kernel for the unlikely case ws_size < packed table.
// ---------------------------------------------------------------------------
__global__ __launch_bounds__(256) void mlmm_elec_kernel(
    const float* __restrict__ dist, const float* __restrict__ vec,
    const float* __restrict__ q_ml, const float* __restrict__ q_mm,
    const float* __restrict__ mu, const float* __restrict__ quad,
    const int* __restrict__ idx_u, const int* __restrict__ idx_v,
    float* __restrict__ out, int n4)
{
    int t = blockIdx.x * blockDim.x + threadIdx.x;
    if (t >= n4) return;
    const float4 r4 = reinterpret_cast<const float4*>(dist)[t];
    const int4   u4 = reinterpret_cast<const int4*>(idx_u)[t];
    const int4   w4 = reinterpret_cast<const int4*>(idx_v)[t];
    const float4 va = reinterpret_cast<const float4*>(vec)[3 * t + 0];
    const float4 vb = reinterpret_cast<const float4*>(vec)[3 * t + 1];
    const float4 vc = reinterpret_cast<const float4*>(vec)[3 * t + 2];
    const float rr[4] = {r4.x, r4.y, r4.z, r4.w};
    const float vx[4] = {va.x, va.w, vb.z, vc.y};
    const float vy[4] = {va.y, vb.x, vb.w, vc.z};
    const float vz[4] = {va.z, vb.y, vc.x, vc.w};
    const int   uu[4] = {u4.x, u4.y, u4.z, u4.w};
    const int   ww[4] = {w4.x, w4.y, w4.z, w4.w};
    float res[4];
#pragma unroll
    for (int k = 0; k < 4; ++k) {
        const float r = rr[k], r2 = r * r;
        const float B0 = 1.0f / r, B1 = B0 / r2, B2 = 3.0f * B1 / r2;
        const int u = uu[k];
        const float qu = q_ml[u], qv = q_mm[ww[k]];
        const float x = vx[k], y = vy[k], z = vz[k];
        const float* m = mu + 3 * u;
        const float g1 = m[0] * x + m[1] * y + m[2] * z;
        const float* Q = quad + 9 * u;
        const float dm = (x * x + y * y + z * z) * (1.0f / 3.0f);
        const float g2 = Q[0] * (x * x - dm) + Q[4] * (y * y - dm) +
                         Q[8] * (z * z - dm) + (Q[1] + Q[3]) * (x * y) +
                         (Q[2] + Q[6]) * (x * z) + (Q[5] + Q[7]) * (y * z);
        res[k] = KE * (B0 * qu * qv + B1 * g1 * qv - B2 * g2 * qv);
    }
    reinterpret_cast<float4*>(out)[t] =
        make_float4(res[0], res[1], res[2], res[3]);
}

extern "C" void kernel_launch(void* const* d_in, const int* in_sizes, int n_in,
                              void* d_out, int out_size, void* d_ws, size_t ws_size,
                              hipStream_t stream) {
    const float* dist  = (const float*)d_in[0];
    const float* vec   = (const float*)d_in[1];
    const float* q_ml  = (const float*)d_in[2];
    const float* q_mm  = (const float*)d_in[3];
    const float* mu    = (const float*)d_in[4];
    const float* quad  = (const float*)d_in[5];
    const int*   idx_u = (const int*)d_in[6];
    const int*   idx_v = (const int*)d_in[7];
    float* out = (float*)d_out;

    const int E    = in_sizes[0];
    const int n_ml = in_sizes[2];
    const int n4   = E / 4;                 // E = 2^24, divisible by 4
    const int block = 256;
    const int grid  = (n4 + block - 1) / block;

    const size_t packed_bytes = (size_t)n_ml * 16 * sizeof(float);

    if (ws_size >= packed_bytes) {
        float* packed = (float*)d_ws;
        pack_ml_kernel<<<(n_ml + 255) / 256, 256, 0, stream>>>(
            q_ml, mu, quad, packed, n_ml);
        mlmm_elec_packed_kernel<<<grid, block, 0, stream>>>(
            dist, vec, packed, q_mm, idx_u, idx_v, out, n4);
    } else {
        mlmm_elec_kernel<<<grid, block, 0, stream>>>(
            dist, vec, q_ml, q_mm, mu, quad, idx_u, idx_v, out, n4);
    }
}

// Round 4
// 200.422 us; speedup vs baseline: 1.9849x; 1.2250x over previous
//
#include <hip/hip_runtime.h>
#include <hip/hip_fp16.h>

#define KE 14.399645351950548f
#define MAX_NML 10000

// ---------------------------------------------------------------------------
// Pack kernel:
//   T1 [n_ml][4] f32  = { KE*q, KE*mux, KE*muy, KE*muz }           (16B rows)
//   T2 [n_ml][6] f16  = 3*KE*{ Q'xx, Q'yy, Q'zz, Qxy+Qyx, Qxz+Qzx, Qyz+Qzy }
//                       (12B rows, traceless correction baked in)
// ---------------------------------------------------------------------------
__global__ __launch_bounds__(256) void pack_ml_kernel2(
    const float* __restrict__ q_ml,
    const float* __restrict__ mu,
    const float* __restrict__ quad,
    float*  __restrict__ t1,        // [n_ml*4] floats
    ushort* __restrict__ t2,        // [n_ml*6] f16 bits
    int n_ml)
{
    int i = blockIdx.x * blockDim.x + threadIdx.x;
    if (i >= n_ml) return;
    const float* Q = quad + 9 * i;
    const float tr3 = (Q[0] + Q[4] + Q[8]) * (1.0f / 3.0f);
    reinterpret_cast<float4*>(t1)[i] =
        make_float4(KE * q_ml[i], KE * mu[3 * i + 0],
                    KE * mu[3 * i + 1], KE * mu[3 * i + 2]);
    const float s = 3.0f * KE;
    ushort* row = t2 + 6 * i;
    row[0] = __half_as_ushort(__float2half_rn(s * (Q[0] - tr3)));
    row[1] = __half_as_ushort(__float2half_rn(s * (Q[4] - tr3)));
    row[2] = __half_as_ushort(__float2half_rn(s * (Q[8] - tr3)));
    row[3] = __half_as_ushort(__float2half_rn(s * (Q[1] + Q[3])));
    row[4] = __half_as_ushort(__float2half_rn(s * (Q[2] + Q[6])));
    row[5] = __half_as_ushort(__float2half_rn(s * (Q[5] + Q[7])));
}

// ---------------------------------------------------------------------------
// Main kernel: quadrupole table lives entirely in LDS (120,000 B);
// per edge only TWO L1/L2 gather touches remain (T1 line + q_mm).
// ---------------------------------------------------------------------------
__global__ __launch_bounds__(1024) void mlmm_elec_lds_kernel(
    const float* __restrict__ dist,      // [E]
    const float* __restrict__ vec,       // [E,3]
    const float* __restrict__ t1,        // [N_ML*4] f32 (KE*q, KE*mu)
    const uint*  __restrict__ t2,        // [N_ML*3] uints (6 f16 per row)
    const float* __restrict__ q_mm,      // [N_MM]
    const int*   __restrict__ idx_u,     // [E]
    const int*   __restrict__ idx_v,     // [E]
    float* __restrict__ out,             // [E]
    int n4, int n_ml)
{
    __shared__ uint sQ[MAX_NML * 3];     // 120,000 B

    // cooperative stage of T2 into LDS
    const int nwords = n_ml * 3;
    for (int i = threadIdx.x; i < nwords; i += blockDim.x)
        sQ[i] = t2[i];
    __syncthreads();

    const int stride = gridDim.x * blockDim.x;
    for (int t = blockIdx.x * blockDim.x + threadIdx.x; t < n4; t += stride) {
        const float4 r4 = reinterpret_cast<const float4*>(dist)[t];
        const int4   u4 = reinterpret_cast<const int4*>(idx_u)[t];
        const int4   w4 = reinterpret_cast<const int4*>(idx_v)[t];
        const float4 va = reinterpret_cast<const float4*>(vec)[3 * t + 0];
        const float4 vb = reinterpret_cast<const float4*>(vec)[3 * t + 1];
        const float4 vc = reinterpret_cast<const float4*>(vec)[3 * t + 2];

        const float rr[4] = {r4.x, r4.y, r4.z, r4.w};
        const float vx[4] = {va.x, va.w, vb.z, vc.y};
        const float vy[4] = {va.y, vb.x, vb.w, vc.z};
        const float vz[4] = {va.z, vb.y, vc.x, vc.w};
        const int   uu[4] = {u4.x, u4.y, u4.z, u4.w};
        const int   ww[4] = {w4.x, w4.y, w4.z, w4.w};

        float res[4];
#pragma unroll
        for (int k = 0; k < 4; ++k) {
            const float r   = rr[k];
            const float B0  = 1.0f / r;
            const float i2  = B0 * B0;
            const float B1  = B0 * i2;          // 1/r^3
            const float B2p = B1 * i2;          // 3/r^5 (x3 baked into table)

            const int u = uu[k];
            const float4 p = reinterpret_cast<const float4*>(t1)[u];
            const float qv = q_mm[ww[k]];

            const uint* qrow = sQ + 3 * u;
            uint a = qrow[0], b = qrow[1], c = qrow[2];
            const float2 f0 = __half22float2(*reinterpret_cast<const __half2*>(&a));
            const float2 f1 = __half22float2(*reinterpret_cast<const __half2*>(&b));
            const float2 f2 = __half22float2(*reinterpret_cast<const __half2*>(&c));

            const float x = vx[k], y = vy[k], z = vz[k];
            const float g1 = p.y * x + p.z * y + p.w * z;
            const float g2 = f0.x * (x * x) + f0.y * (y * y) + f1.x * (z * z)
                           + f1.y * (x * y) + f2.x * (x * z) + f2.y * (y * z);

            res[k] = qv * (B0 * p.x + B1 * g1 - B2p * g2);
        }

        reinterpret_cast<float4*>(out)[t] =
            make_float4(res[0], res[1], res[2], res[3]);
    }
}

// ---------------------------------------------------------------------------
// Fallback: round-2 packed kernel (one 64B f32 line per ML gather).
// ---------------------------------------------------------------------------
__global__ __launch_bounds__(256) void pack_ml_kernel(
    const float* __restrict__ q_ml, const float* __restrict__ mu,
    const float* __restrict__ quad, float* __restrict__ packed, int n_ml)
{
    int i = blockIdx.x * blockDim.x + threadIdx.x;
    if (i >= n_ml) return;
    const float* Q = quad + 9 * i;
    const float tr3 = (Q[0] + Q[4] + Q[8]) * (1.0f / 3.0f);
    float4* p = reinterpret_cast<float4*>(packed + 16 * i);
    p[0] = make_float4(q_ml[i], mu[3 * i + 0], mu[3 * i + 1], mu[3 * i + 2]);
    p[1] = make_float4(Q[0] - tr3, Q[4] - tr3, Q[8] - tr3, Q[1] + Q[3]);
    p[2] = make_float4(Q[2] + Q[6], Q[5] + Q[7], 0.0f, 0.0f);
}

__global__ __launch_bounds__(256) void mlmm_elec_packed_kernel(
    const float* __restrict__ dist, const float* __restrict__ vec,
    const float* __restrict__ packed, const float* __restrict__ q_mm,
    const int* __restrict__ idx_u, const int* __restrict__ idx_v,
    float* __restrict__ out, int n4)
{
    int t = blockIdx.x * blockDim.x + threadIdx.x;
    if (t >= n4) return;
    const float4 r4 = reinterpret_cast<const float4*>(dist)[t];
    const int4   u4 = reinterpret_cast<const int4*>(idx_u)[t];
    const int4   w4 = reinterpret_cast<const int4*>(idx_v)[t];
    const float4 va = reinterpret_cast<const float4*>(vec)[3 * t + 0];
    const float4 vb = reinterpret_cast<const float4*>(vec)[3 * t + 1];
    const float4 vc = reinterpret_cast<const float4*>(vec)[3 * t + 2];
    const float rr[4] = {r4.x, r4.y, r4.z, r4.w};
    const float vx[4] = {va.x, va.w, vb.z, vc.y};
    const float vy[4] = {va.y, vb.x, vb.w, vc.z};
    const float vz[4] = {va.z, vb.y, vc.x, vc.w};
    const int   uu[4] = {u4.x, u4.y, u4.z, u4.w};
    const int   ww[4] = {w4.x, w4.y, w4.z, w4.w};
    float res[4];
#pragma unroll
    for (int k = 0; k < 4; ++k) {
        const float r = rr[k], r2 = r * r;
        const float B0 = 1.0f / r, B1 = B0 / r2, B2 = 3.0f * B1 / r2;
        const float4* p = reinterpret_cast<const float4*>(packed + 16 * uu[k]);
        const float4 p0 = p[0], p1 = p[1], p2v = p[2];
        const float qv = q_mm[ww[k]];
        const float x = vx[k], y = vy[k], z = vz[k];
        const float g1 = p0.y * x + p0.z * y + p0.w * z;
        const float g2 = p1.x * (x * x) + p1.y * (y * y) + p1.z * (z * z)
                       + p1.w * (x * y) + p2v.x * (x * z) + p2v.y * (y * z);
        res[k] = KE * qv * (B0 * p0.x + B1 * g1 - B2 * g2);
    }
    reinterpret_cast<float4*>(out)[t] =
        make_float4(res[0], res[1], res[2], res[3]);
}

extern "C" void kernel_launch(void* const* d_in, const int* in_sizes, int n_in,
                              void* d_out, int out_size, void* d_ws, size_t ws_size,
                              hipStream_t stream) {
    const float* dist  = (const float*)d_in[0];
    const float* vec   = (const float*)d_in[1];
    const float* q_ml  = (const float*)d_in[2];
    const float* q_mm  = (const float*)d_in[3];
    const float* mu    = (const float*)d_in[4];
    const float* quad  = (const float*)d_in[5];
    const int*   idx_u = (const int*)d_in[6];
    const int*   idx_v = (const int*)d_in[7];
    float* out = (float*)d_out;

    const int E    = in_sizes[0];
    const int n_ml = in_sizes[2];
    const int n4   = E / 4;                 // E = 2^24, divisible by 4

    // workspace layout: T1 (16B rows) | T2 (12B rows, 4B-aligned)
    const size_t t1_bytes = (size_t)n_ml * 16;
    const size_t t2_bytes = (size_t)n_ml * 12;

    if (n_ml <= MAX_NML && ws_size >= t1_bytes + t2_bytes) {
        float*  t1 = (float*)d_ws;
        ushort* t2 = (ushort*)((char*)d_ws + t1_bytes);
        pack_ml_kernel2<<<(n_ml + 255) / 256, 256, 0, stream>>>(
            q_ml, mu, quad, t1, t2, n_ml);
        const int block = 1024;
        const int grid  = 256;              // 1 block/CU, zero re-staging
        mlmm_elec_lds_kernel<<<grid, block, 0, stream>>>(
            dist, vec, t1, (const uint*)t2, q_mm, idx_u, idx_v, out, n4, n_ml);
    } else if (ws_size >= (size_t)n_ml * 16 * sizeof(float)) {
        float* packed = (float*)d_ws;
        pack_ml_kernel<<<(n_ml + 255) / 256, 256, 0, stream>>>(
            q_ml, mu, quad, packed, n_ml);
        mlmm_elec_packed_kernel<<<(n4 + 255) / 256, 256, 0, stream>>>(
            dist, vec, packed, q_mm, idx_u, idx_v, out, n4);
    }
}